// Round 8
// baseline (90.002 us; speedup 1.0000x reference)
//
#include <hip/hip_runtime.h>

// Additive RQ kernel, symmetric: covar[i,j] = os * sum_d (1 + ((x_i,d-x_j,d)/l_d)^2/(2a))^(-a)
// Output layout: [ mean (N floats, zeros) | covar (N*N floats) ]
// Upper-triangle 32x32 tiles; mirror via LDS transpose.
//
// pow(t,-a) via exponent/mantissa split (no cvt/floor/trans in inner loop):
//   t = m * 2^(e-127), m in [1,2)  =>  t^(-a) = m^(-a) * 2^(-a*(e-127))
//   2^(-a*(e-127)): 160-entry LDS table indexed by raw exponent byte; live
//     entries (e=127..135) sit in distinct banks, same-entry lanes broadcast.
//   m^(-a): degree-7 Chebyshev-node interpolant, monomial form IN m (no
//     recentring), coeffs built once per thread via Newton divided differences.
// RESIDENCY FIX vs prev round (VGPR=28 proved compiler folded operands back
// into per-term LDS reads): B-row now loaded from GLOBAL into registers
// (compiler won't rematerialize global loads); Bs LDS array deleted; A-row
// read as one ds_read_b128 per 4 terms; __launch_bounds__(256,4) lifts the
// VGPR cap to 128 so the ~80-reg working set fits.
// Inner loop: 13 full-rate VALU + 1 conflict-free ds_read per term.
// Per-term err ~3e-5 (interp) -> negligible vs 0.577 threshold.

#define D 32
#define TILE 32

#if __has_builtin(__builtin_amdgcn_exp2f)
#define EXP2F(x) __builtin_amdgcn_exp2f(x)
#else
#define EXP2F(x) exp2f(x)
#endif
#if __has_builtin(__builtin_amdgcn_logf)
#define LOG2F(x) __builtin_amdgcn_logf(x)
#else
#define LOG2F(x) __log2f(x)
#endif

__global__ __launch_bounds__(256, 4) void rq_covar_sym_kernel(
    const float* __restrict__ x,
    const float* __restrict__ ls,
    const float* __restrict__ alpha_p,
    const float* __restrict__ os_p,
    float* __restrict__ mean_out,
    float* __restrict__ covar,
    int n, int ntiles)
{
    __shared__ float As[TILE][36];
    __shared__ float pow2tab[160];   // indexed by raw exponent byte (bits>>23)

    const int t = threadIdx.x;
    const int k = blockIdx.x;

    // fold mean zeroing into the first ceil(n/256) blocks
    {
        const int idx = k * 256 + t;
        if (idx < n) mean_out[idx] = 0.0f;
    }

    // closed-form upper-triangle decode (bi <= bj)
    const float nt = (float)ntiles;
    int bi = (int)(nt + 0.5f - sqrtf((nt + 0.5f) * (nt + 0.5f) - 2.0f * (float)k));
    while (bi > 0 && k < bi * ntiles - (bi * (bi - 1)) / 2) --bi;
    while (k >= (bi + 1) * ntiles - ((bi + 1) * bi) / 2) ++bi;
    const int bj = bi + (k - (bi * ntiles - (bi * (bi - 1)) / 2));

    const float alpha = alpha_p[0];
    const float oscale = os_p[0];
    const float nalpha = -alpha;
    const float rs2a = rsqrtf(2.0f * alpha);

    // 2^(nalpha * (e-127)) table; only entries 127..135 are ever read.
    for (int e = t; e < 160; e += 256)
        pow2tab[e] = EXP2F(nalpha * (float)(e - 127));

    // ---- B-row straight from global into REGISTERS (pre-scaled) ----
    const int c = t & 31;
    const int r0 = t >> 5;
    float bs[D];
    {
        const float* bp = x + (size_t)(bj * TILE + c) * D;
#pragma unroll
        for (int q = 0; q < D; q += 4) {
            const float4 bv = *reinterpret_cast<const float4*>(bp + q);
            const float4 lv = *reinterpret_cast<const float4*>(ls + q);
            bs[q + 0] = bv.x * (rs2a / lv.x);
            bs[q + 1] = bv.y * (rs2a / lv.y);
            bs[q + 2] = bv.z * (rs2a / lv.z);
            bs[q + 3] = bv.w * (rs2a / lv.w);
        }
    }

    // ---- degree-7 interpolant of m^(-alpha) on [1,2), monomial in m ----
    const float Xc[8] = {1.990393f, 1.915735f, 1.777785f, 1.597545f,
                         1.402455f, 1.222215f, 1.084265f, 1.009607f};
    float dd[8];
#pragma unroll
    for (int i = 0; i < 8; ++i)
        dd[i] = EXP2F(nalpha * LOG2F(Xc[i]));
#pragma unroll
    for (int j = 1; j < 8; ++j) {
#pragma unroll
        for (int i = 7; i >= 1; --i) {
            if (i >= j)
                dd[i] = (dd[i] - dd[i - 1]) * (1.0f / (Xc[i] - Xc[i - j]));
        }
    }
    float C[8] = {0.0f, 0.0f, 0.0f, 0.0f, 0.0f, 0.0f, 0.0f, 0.0f};
    C[0] = dd[7];
#pragma unroll
    for (int i = 6; i >= 0; --i) {
        const float yi = Xc[i];
#pragma unroll
        for (int kk = 7; kk >= 1; --kk)
            C[kk] = fmaf(-yi, C[kk], C[kk - 1]);
        C[0] = fmaf(-yi, C[0], dd[i]);
    }

    // ---- stage A tile (scaled) into LDS ----
    {
        const int row = t >> 3;
        const int q = (t & 7) * 4;
        const float4 lv = *reinterpret_cast<const float4*>(&ls[q]);
        const float4 a = *reinterpret_cast<const float4*>(&x[(size_t)(bi * TILE + row) * D + q]);
        As[row][q + 0] = a.x * (rs2a / lv.x);
        As[row][q + 1] = a.y * (rs2a / lv.y);
        As[row][q + 2] = a.z * (rs2a / lv.z);
        As[row][q + 3] = a.w * (rs2a / lv.w);
    }
    __syncthreads();

    float acc[4];
#pragma unroll
    for (int kk = 0; kk < 4; ++kk) {
        const int r = r0 + kk * 8;
        float s0 = 0.0f, s1 = 0.0f, s2 = 0.0f, s3 = 0.0f;
#pragma unroll
        for (int d = 0; d < D; d += 4) {
            const float4 av = *reinterpret_cast<const float4*>(&As[r][d]);
#pragma unroll
            for (int j = 0; j < 4; ++j) {
                const float a_j = (j == 0) ? av.x : (j == 1) ? av.y : (j == 2) ? av.z : av.w;
                const float diff = a_j - bs[d + j];
                const float tv = fmaf(diff, diff, 1.0f);
                const unsigned bits = __float_as_uint(tv);
                const float pw = pow2tab[bits >> 23];      // conflict-free gather
                const float m = __uint_as_float((bits & 0x7FFFFFu) | 0x3F800000u);
                float p = fmaf(C[7], m, C[6]);
                p = fmaf(p, m, C[5]);
                p = fmaf(p, m, C[4]);
                p = fmaf(p, m, C[3]);
                p = fmaf(p, m, C[2]);
                p = fmaf(p, m, C[1]);
                p = fmaf(p, m, C[0]);
                if (j == 0) s0 = fmaf(p, pw, s0);
                else if (j == 1) s1 = fmaf(p, pw, s1);
                else if (j == 2) s2 = fmaf(p, pw, s2);
                else s3 = fmaf(p, pw, s3);
            }
        }
        acc[kk] = oscale * ((s0 + s1) + (s2 + s3));
    }

    // direct (coalesced) write of own tile
#pragma unroll
    for (int kk = 0; kk < 4; ++kk) {
        const int r = r0 + kk * 8;
        covar[(size_t)(bi * TILE + r) * n + (bj * TILE + c)] = acc[kk];
    }

    // mirror write for off-diagonal tiles: transpose through LDS (reuse As)
    if (bi != bj) {
        __syncthreads();
#pragma unroll
        for (int kk = 0; kk < 4; ++kk) {
            As[r0 + kk * 8][c] = acc[kk];
        }
        __syncthreads();
#pragma unroll
        for (int kk = 0; kk < 4; ++kk) {
            const int rr = r0 + kk * 8;
            const float v = As[c][rr];
            covar[(size_t)(bj * TILE + rr) * n + (bi * TILE + c)] = v;
        }
    }
}

extern "C" void kernel_launch(void* const* d_in, const int* in_sizes, int n_in,
                              void* d_out, int out_size, void* d_ws, size_t ws_size,
                              hipStream_t stream) {
    const float* x = (const float*)d_in[0];
    const float* ls = (const float*)d_in[1];
    const float* alpha_p = (const float*)d_in[2];
    const float* os_p = (const float*)d_in[3];

    const int n = in_sizes[0] / D;       // 2048
    const int ntiles = n / TILE;         // 64
    const int nblocks = ntiles * (ntiles + 1) / 2;  // 2080

    float* mean_out = (float*)d_out;
    float* covar = (float*)d_out + n;

    rq_covar_sym_kernel<<<nblocks, 256, 0, stream>>>(x, ls, alpha_p, os_p,
                                                     mean_out, covar, n, ntiles);
}